// Round 1
// baseline (319.793 us; speedup 1.0000x reference)
//
#include <hip/hip_runtime.h>

#define BATCH 16
#define CIN   64
#define HW    128
#define OC    128
#define KSIZE 576   // 64 * 9

typedef float  float4v __attribute__((ext_vector_type(4)));
typedef short  short4v __attribute__((ext_vector_type(4)));
typedef __bf16 bfrag   __attribute__((ext_vector_type(8)));

// workspace layout (float offsets)
#define WS_ACT    0      // act_scale[576]
#define WS_WSC    576    // weight_scale[576]
#define WS_SCALE  1152   // scale[576] (original k order: k = c*9 + r)
#define WS_XMUL   1728   // xmul permuted [r][c]: 1/(scale[c*9+r]*s_x)
#define WS_SX     2304
#define WS_SW     2305
#define WS_SXSW   2306
#define WS_WQ_BYTES 65536  // bf16 wq[o][k'] with k' = r*64+c, 128*576*2 B

// ---------------------------------------------------------------------------
// Kernel 1: act_scale via boundary-category maxima. One block per (channel, batch).
// act_scale[c*9 + kh*3 + kw] = max |input[b,c,h,w]| over h in H(kh), w in W(kw)
//   H(0)=[0,126], H(1)=[0,127], H(2)=[1,127]  (same for W)
// ---------------------------------------------------------------------------
__global__ __launch_bounds__(256) void k_act(const float* __restrict__ in,
                                             float* __restrict__ wsf) {
    const int c = blockIdx.x >> 4, bs = blockIdx.x & 15;
    const float* p = in + (size_t)(bs * CIN + c) * (HW * HW);
    float m[9];
#pragma unroll
    for (int i = 0; i < 9; ++i) m[i] = 0.f;
    for (int e = threadIdx.x; e < HW * HW; e += 256) {
        const int h = e >> 7, w = e & 127;
        const float v = fabsf(p[e]);
        const float vh0 = (h <= 126) ? v : 0.f;   // rows valid for kh=0
        const float vh1 = v;                       // kh=1: all rows
        const float vh2 = (h >= 1) ? v : 0.f;     // kh=2
        const bool w0 = (w <= 126), w2 = (w >= 1);
        m[0] = fmaxf(m[0], w0 ? vh0 : 0.f);
        m[1] = fmaxf(m[1], vh0);
        m[2] = fmaxf(m[2], w2 ? vh0 : 0.f);
        m[3] = fmaxf(m[3], w0 ? vh1 : 0.f);
        m[4] = fmaxf(m[4], vh1);
        m[5] = fmaxf(m[5], w2 ? vh1 : 0.f);
        m[6] = fmaxf(m[6], w0 ? vh2 : 0.f);
        m[7] = fmaxf(m[7], vh2);
        m[8] = fmaxf(m[8], w2 ? vh2 : 0.f);
    }
    __shared__ float red[256];
    for (int i = 0; i < 9; ++i) {
        red[threadIdx.x] = m[i];
        __syncthreads();
        for (int s = 128; s > 0; s >>= 1) {
            if (threadIdx.x < s) red[threadIdx.x] = fmaxf(red[threadIdx.x], red[threadIdx.x + s]);
            __syncthreads();
        }
        if (threadIdx.x == 0) {
            // values are non-negative floats: int-bit atomicMax == float max.
            // ws poison 0xAAAAAAAA is a negative int, so no pre-zero needed.
            atomicMax((int*)(wsf + WS_ACT + c * 9 + i), __float_as_int(red[0]));
        }
        __syncthreads();
    }
}

// ---------------------------------------------------------------------------
// Kernel 2: weight_scale[k] = max_o |w_flat[o,k]|
// ---------------------------------------------------------------------------
__global__ void k_wscale(const float* __restrict__ w, float* __restrict__ wsf) {
    const int k = blockIdx.x * 64 + threadIdx.x;   // grid 9 x 64 = 576
    float m = 0.f;
    for (int o = 0; o < OC; ++o) m = fmaxf(m, fabsf(w[o * KSIZE + k]));
    wsf[WS_WSC + k] = m;
}

// ---------------------------------------------------------------------------
// Kernel 3: scale[k], amax_x = max_k act/scale, amax_w = max_k wsc*scale,
// s_x, s_w, s_x*s_w, and permuted xmul. Single block of 576 threads.
// ---------------------------------------------------------------------------
__global__ void k_scale(float* __restrict__ wsf) {
    __shared__ float l1[1024], l2[1024];
    const int t = threadIdx.x;
    const float a  = wsf[WS_ACT + t];
    const float wv = wsf[WS_WSC + t];
    float s = sqrtf(a) / sqrtf(wv);
    if (s == 0.f) s = 1.f;
    wsf[WS_SCALE + t] = s;
    l1[t] = a / s;       // exact: max_n |x/scale| column max
    l2[t] = wv * s;      // exact: max_o |w*scale| column max
    if (t < 448) { l1[576 + t] = 0.f; l2[576 + t] = 0.f; }
    __syncthreads();
    for (int st = 512; st > 0; st >>= 1) {
        if (t < st) {
            l1[t] = fmaxf(l1[t], l1[t + st]);
            l2[t] = fmaxf(l2[t], l2[t + st]);
        }
        __syncthreads();
    }
    if (t == 0) {
        const float ax = l1[0], aw = l2[0];
        const float sx = ax > 0.f ? ax / 127.f : 1.f;
        const float sw = aw > 0.f ? aw / 127.f : 1.f;
        wsf[WS_SX] = sx; wsf[WS_SW] = sw; wsf[WS_SXSW] = sx * sw;
        l1[0] = sx;
    }
    __syncthreads();
    const float sx = l1[0];
    const int r = t % 9, c = t / 9;                 // K-permutation k' = r*64 + c
    wsf[WS_XMUL + r * 64 + c] = 1.0f / (s * sx);
}

// ---------------------------------------------------------------------------
// Kernel 4: quantize weights -> bf16 integer values, permuted layout wq[o][r*64+c]
// ---------------------------------------------------------------------------
__global__ void k_wq(const float* __restrict__ w, const float* __restrict__ wsf,
                     short* __restrict__ wq) {
    const int o = blockIdx.x, k2 = threadIdx.x;     // grid 128 x 576
    const int r = k2 >> 6, c = k2 & 63;
    const int ko = c * 9 + r;
    const float s  = wsf[WS_SCALE + ko];
    const float sw = wsf[WS_SW];
    float q = rintf((w[o * KSIZE + ko] * s) / sw);  // same op order as reference
    q = fminf(127.f, fmaxf(-127.f, q));
    // |q| <= 127 is exact in bf16: truncate mantissa
    wq[o * KSIZE + k2] = (short)(__float_as_uint(q) >> 16);
}

// ---------------------------------------------------------------------------
// Kernel 5: implicit-GEMM conv. Block = one output row (b, oh): M=128 (ow),
// N=128 (o), K=576 in 9 chunks of 64 (chunk r=(kh,kw), k within = channel c).
// A quantized on the fly fp32->bf16 into LDS [ow][c] (XOR-swizzled, pad 72).
// Exact integer bf16 MFMA, epilogue scales by s_x*s_w, direct float4 stores.
// ---------------------------------------------------------------------------
__global__ __launch_bounds__(256) void k_gemm(const float* __restrict__ in,
                                              const short* __restrict__ wq,
                                              const float* __restrict__ wsf,
                                              float* __restrict__ out) {
    __shared__ short A_l[128 * 72];   // [ow][c], row stride 72 shorts = 144 B
    __shared__ short B_l[128 * 72];   // [o][c]
    const int tid = threadIdx.x;
    const int lane = tid & 63, wave = tid >> 6;
    const int b = blockIdx.x >> 7, oh = blockIdx.x & 127;
    const int wm = (wave & 1) << 6, wn = (wave >> 1) << 6;  // 64x64 wave tile
    const float* xmul = wsf + WS_XMUL;

    float4v acc[4][4];
    const float4v zero4 = {0.f, 0.f, 0.f, 0.f};
#pragma unroll
    for (int i = 0; i < 4; ++i)
#pragma unroll
        for (int j = 0; j < 4; ++j) acc[i][j] = zero4;

    for (int r = 0; r < 9; ++r) {
        const int kh = r / 3, kw = r - kh * 3;
        const int h = oh + kh - 1;
        if (h >= 0 && h < HW) {        // uniform branch; skipped chunk == all-zero A
            {   // --- B staging: copy wq rows for this chunk (L2-resident) ---
                const int o = tid >> 1, seg = tid & 1;
                const uint4* src = (const uint4*)(wq + o * KSIZE + r * 64 + seg * 32);
                uint4* dst = (uint4*)(B_l + o * 72 + seg * 32);
#pragma unroll
                for (int i = 0; i < 4; ++i) dst[i] = src[i];
            }
            // --- A staging: coalesced float4 row loads, quantize, 4x4 register
            // transpose, swizzled short4 LDS writes ---
#pragma unroll
            for (int half = 0; half < 2; ++half) {
                const int bb = tid + half * 256;
                const int ow0 = (bb & 31) << 2;
                const int c0 = (bb >> 5) << 2;
                const float* ip = in + ((size_t)(b * CIN + c0) * HW + h) * HW + ow0;
                const float4v xm = *(const float4v*)(xmul + r * 64 + c0);
                float4v v[4];
#pragma unroll
                for (int i = 0; i < 4; ++i) v[i] = *(const float4v*)(ip + i * (HW * HW));
                short qs[4][4];
#pragma unroll
                for (int i = 0; i < 4; ++i) {
#pragma unroll
                    for (int j = 0; j < 4; ++j) {
                        float q = rintf(v[i][j] * xm[i]);
                        q = fminf(127.f, fmaxf(-127.f, q));
                        qs[i][j] = (short)(__float_as_uint(q) >> 16);
                    }
                }
#pragma unroll
                for (int j = 0; j < 4; ++j) {
                    const int ow = ow0 + j + 1 - kw;   // shift by kw applied on write
                    if (ow >= 0 && ow < HW) {
                        short4v pk = {qs[0][j], qs[1][j], qs[2][j], qs[3][j]};
                        const int pc = c0 ^ (((ow >> 2) & 7) << 3);  // bank swizzle
                        *(short4v*)(A_l + ow * 72 + pc) = pk;
                    }
                }
            }
            // zero-fill the padding column nobody writes
            if (kw == 0 && tid < 16) {
                short4v z = {0, 0, 0, 0};
                *(short4v*)(A_l + (tid << 2)) = z;                       // ow=0, swz=0
            }
            if (kw == 2 && tid < 16) {
                short4v z = {0, 0, 0, 0};
                *(short4v*)(A_l + 127 * 72 + ((tid << 2) ^ 56)) = z;     // ow=127, swz=56
            }
            __syncthreads();
            // --- MFMA: 2 K-steps of 32, 4x4 16x16 tiles per wave ---
#pragma unroll
            for (int ks = 0; ks < 2; ++ks) {
                const int klog = (ks << 5) + ((lane >> 4) << 3);
                bfrag af[4], bfr[4];
#pragma unroll
                for (int mt = 0; mt < 4; ++mt) {
                    const int arow = wm + (mt << 4) + (lane & 15);
                    const int pk2 = klog ^ (((arow >> 2) & 7) << 3);
                    af[mt] = *(const bfrag*)(A_l + arow * 72 + pk2);
                }
#pragma unroll
                for (int nt = 0; nt < 4; ++nt) {
                    const int brow = wn + (nt << 4) + (lane & 15);
                    bfr[nt] = *(const bfrag*)(B_l + brow * 72 + klog);
                }
#pragma unroll
                for (int mt = 0; mt < 4; ++mt)
#pragma unroll
                    for (int nt = 0; nt < 4; ++nt)
                        acc[mt][nt] = __builtin_amdgcn_mfma_f32_16x16x32_bf16(
                            af[mt], bfr[nt], acc[mt][nt], 0, 0, 0);
            }
            __syncthreads();
        }
    }
    // --- epilogue: D row=(lane>>4)*4+j -> ow (4 consecutive), col=lane&15 -> o.
    // float4 stores: 16 fully-used 64B lines per instruction.
    const float sxsw = wsf[WS_SXSW];
#pragma unroll
    for (int mt = 0; mt < 4; ++mt) {
#pragma unroll
        for (int nt = 0; nt < 4; ++nt) {
            const int ow0 = wm + (mt << 4) + ((lane >> 4) << 2);
            const int o = wn + (nt << 4) + (lane & 15);
            float4v rv;
#pragma unroll
            for (int q = 0; q < 4; ++q) rv[q] = acc[mt][nt][q] * sxsw;
            *(float4v*)(out + ((size_t)(b * OC + o) * HW + oh) * HW + ow0) = rv;
        }
    }
}

// ---------------------------------------------------------------------------
extern "C" void kernel_launch(void* const* d_in, const int* in_sizes, int n_in,
                              void* d_out, int out_size, void* d_ws, size_t ws_size,
                              hipStream_t stream) {
    const float* in = (const float*)d_in[0];   // (16, 64, 128, 128) fp32
    const float* wt = (const float*)d_in[1];   // (128, 64, 3, 3) fp32
    float* out = (float*)d_out;                // (16, 128, 128, 128) fp32
    float* wsf = (float*)d_ws;
    short* wq = (short*)((char*)d_ws + WS_WQ_BYTES);

    k_act<<<dim3(64 * 16), dim3(256), 0, stream>>>(in, wsf);
    k_wscale<<<dim3(9), dim3(64), 0, stream>>>(wt, wsf);
    k_scale<<<dim3(1), dim3(576), 0, stream>>>(wsf);
    k_wq<<<dim3(128), dim3(576), 0, stream>>>(wt, wsf, wq);
    k_gemm<<<dim3(BATCH * HW), dim3(256), 0, stream>>>(in, wq, wsf, out);
}

// Round 2
// 266.328 us; speedup vs baseline: 1.2008x; 1.2008x over previous
//
#include <hip/hip_runtime.h>

#define BATCH 16
#define CIN   64
#define HW    128
#define OC    128
#define KSIZE 576   // 64 * 9

typedef float  float4v __attribute__((ext_vector_type(4)));
typedef short  short4v __attribute__((ext_vector_type(4)));
typedef __bf16 bfrag   __attribute__((ext_vector_type(8)));

// workspace layout (float offsets)
#define WS_ACT   0      // act_scale[576], k = c*9 + r order
#define WS_WSC   576    // weight_scale[576]
#define WS_XMUL  1152   // xmul[r*64+c] = 1/(scale[c*9+r]*s_x)
#define WS_SXSW  1728
#define WS_WQ_BYTE_OFF 8192   // bf16 wq_s[9][128][64], rows XOR-pre-swizzled

__device__ __forceinline__ void async_cp16(const void* g, void* l) {
    __builtin_amdgcn_global_load_lds(
        (const __attribute__((address_space(1))) unsigned int*)g,
        (__attribute__((address_space(3))) unsigned int*)l, 16, 0, 0);
}

// ---------------------------------------------------------------------------
// Kernel 1: fused absmax. Blocks [0,1024): act_scale boundary-category maxima
// (float4 loads). Blocks [1024,1168): weight_scale, one wave per k-column.
// ---------------------------------------------------------------------------
__global__ __launch_bounds__(256) void k_absmax(const float* __restrict__ in,
                                                const float* __restrict__ w,
                                                float* __restrict__ wsf) {
    const int tid = threadIdx.x, lane = tid & 63, wid = tid >> 6;
    if (blockIdx.x < 1024) {
        const int c = blockIdx.x >> 4, bs = blockIdx.x & 15;
        const float4v* p = (const float4v*)(in + (size_t)(bs * CIN + c) * (HW * HW));
        float m[9];
#pragma unroll
        for (int i = 0; i < 9; ++i) m[i] = 0.f;
        for (int e = tid; e < 4096; e += 256) {          // 16 iters
            const int h = e >> 5, q = e & 31;
            const float4v v = p[e];
            const float a0 = fabsf(v[0]), a1 = fabsf(v[1]), a2 = fabsf(v[2]), a3 = fabsf(v[3]);
            const float m01 = fmaxf(a0, a1), m12 = fmaxf(a1, a2);
            const float mall = fmaxf(m01, fmaxf(a2, a3));
            const float mw0 = (q == 31) ? fmaxf(m01, a2) : mall;   // w<=126
            const float mw2 = (q == 0)  ? fmaxf(m12, a3) : mall;   // w>=1
            const bool h0 = (h <= 126), h2 = (h >= 1);
            m[0] = fmaxf(m[0], h0 ? mw0 : 0.f);
            m[1] = fmaxf(m[1], h0 ? mall : 0.f);
            m[2] = fmaxf(m[2], h0 ? mw2 : 0.f);
            m[3] = fmaxf(m[3], mw0);
            m[4] = fmaxf(m[4], mall);
            m[5] = fmaxf(m[5], mw2);
            m[6] = fmaxf(m[6], h2 ? mw0 : 0.f);
            m[7] = fmaxf(m[7], h2 ? mall : 0.f);
            m[8] = fmaxf(m[8], h2 ? mw2 : 0.f);
        }
#pragma unroll
        for (int i = 0; i < 9; ++i)
            for (int off = 32; off; off >>= 1)
                m[i] = fmaxf(m[i], __shfl_down(m[i], off));
        __shared__ float sred[4][9];
        if (lane == 0)
#pragma unroll
            for (int i = 0; i < 9; ++i) sred[wid][i] = m[i];
        __syncthreads();
        if (tid < 9) {
            float mm = fmaxf(fmaxf(sred[0][tid], sred[1][tid]),
                             fmaxf(sred[2][tid], sred[3][tid]));
            // non-negative floats: int-bit atomicMax == float max; 0xAA poison is
            // a negative int so no pre-zero needed.
            atomicMax((int*)(wsf + WS_ACT + c * 9 + tid), __float_as_int(mm));
        }
    } else {
        const int k = (blockIdx.x - 1024) * 4 + wid;     // 144 blocks * 4 waves = 576
        float m = fmaxf(fabsf(w[lane * KSIZE + k]), fabsf(w[(lane + 64) * KSIZE + k]));
        for (int off = 32; off; off >>= 1) m = fmaxf(m, __shfl_down(m, off));
        if (lane == 0) wsf[WS_WSC + k] = m;
    }
}

// ---------------------------------------------------------------------------
// Kernel 2: per-block redundant scale reduction + weight quantize.
// grid 128 (one block per o), 576 threads. Block 0 also writes xmul/sxsw.
// wq_s global layout pre-swizzled: [r][o][c ^ ((o&7)<<3)] so the gemm's
// global_load_lds DMA lands conflict-free in LDS.
// ---------------------------------------------------------------------------
__global__ __launch_bounds__(576) void k_scale_wq(const float* __restrict__ w,
                                                  float* __restrict__ wsf,
                                                  short* __restrict__ wq_s) {
    __shared__ float ls[576];
    __shared__ float redA[9], redB[9];
    const int t = threadIdx.x, o = blockIdx.x;
    const int lane = t & 63, wid = t >> 6;
    const float a = wsf[WS_ACT + t];
    const float wv = wsf[WS_WSC + t];
    float s = sqrtf(a) / sqrtf(wv);
    if (s == 0.f) s = 1.f;
    ls[t] = s;
    float v1 = a / s;     // exact column max of |x/scale|
    float v2 = wv * s;    // exact column max of |w*scale|
    for (int off = 32; off; off >>= 1) {
        v1 = fmaxf(v1, __shfl_down(v1, off));
        v2 = fmaxf(v2, __shfl_down(v2, off));
    }
    if (lane == 0) { redA[wid] = v1; redB[wid] = v2; }
    __syncthreads();
    float ax = redA[0], aw = redB[0];
#pragma unroll
    for (int i = 1; i < 9; ++i) { ax = fmaxf(ax, redA[i]); aw = fmaxf(aw, redB[i]); }
    const float sx = ax > 0.f ? ax / 127.f : 1.f;
    const float sw = aw > 0.f ? aw / 127.f : 1.f;
    const int r = t >> 6, c = t & 63, ko = c * 9 + r;
    float q = rintf((w[o * KSIZE + ko] * ls[ko]) / sw);   // same op order as reference
    q = fminf(127.f, fmaxf(-127.f, q));
    // |q|<=127 exact in bf16 via truncation
    wq_s[r * 8192 + o * 64 + (c ^ ((o & 7) << 3))] = (short)(__float_as_uint(q) >> 16);
    if (o == 0) {
        wsf[WS_XMUL + t] = 1.0f / (ls[ko] * sx);
        if (t == 0) wsf[WS_SXSW] = sx * sw;
    }
}

// ---------------------------------------------------------------------------
// Kernel 3: pipelined implicit-GEMM conv. Block = one output row (b,oh):
// M=128(ow), N=128(o), K=9 chunks of 64(c). Double-buffered LDS, one barrier
// per chunk; A prefetched into VGPRs, B via async global_load_lds (pre-swizzled
// in global). All in-flight vmem at each barrier has had ~1 MFMA phase of cover.
// ---------------------------------------------------------------------------
__global__ __launch_bounds__(256, 2) void k_gemm(const float* __restrict__ in,
                                                 const short* __restrict__ wq_s,
                                                 const float* __restrict__ wsf,
                                                 float* __restrict__ out) {
    __shared__ short A_l[2][128 * 72];   // [ow][c], padded rows, XOR-swizzled
    __shared__ short B_l[2][128 * 64];   // [o][c], XOR-swizzled (done in global)
    const int tid = threadIdx.x;
    const int lane = tid & 63, wave = tid >> 6;
    const int b = blockIdx.x >> 7, oh = blockIdx.x & 127;
    const int wm = (wave & 1) << 6, wn = (wave >> 1) << 6;
    const float* xmul = wsf + WS_XMUL;

    float4v acc[4][4];
    const float4v zero4 = {0.f, 0.f, 0.f, 0.f};
#pragma unroll
    for (int i = 0; i < 4; ++i)
#pragma unroll
        for (int j = 0; j < 4; ++j) acc[i][j] = zero4;

    float4v Av[2][4];   // A prefetch: 2 halves x 4 channels of float4 = 32 VGPR

    auto issue_B = [&](int r, short* Bbuf) {
        const short* src = wq_s + r * 8192 + tid * 8;   // tid*16 bytes
#pragma unroll
        for (int i = 0; i < 4; ++i)
            async_cp16(src + i * 2048, Bbuf + tid * 8 + i * 2048);
    };
    auto issue_A = [&](int r) {
        const int kh = r / 3;
        int h = oh + kh - 1;
        h = h < 0 ? 0 : (h > HW - 1 ? HW - 1 : h);      // clamp; invalid zeroed later
#pragma unroll
        for (int half = 0; half < 2; ++half) {
            const int bb = tid + half * 256;
            const int ow0 = (bb & 31) << 2, c0 = (bb >> 5) << 2;
            const float* ip = in + ((size_t)(b * CIN + c0) * HW + h) * HW + ow0;
#pragma unroll
            for (int i = 0; i < 4; ++i) Av[half][i] = *(const float4v*)(ip + i * (HW * HW));
        }
    };

    issue_A(0);
    issue_B(0, B_l[0]);

    for (int r = 0; r < 9; ++r) {
        const int buf = r & 1;
        const int kh = r / 3, kw = r - kh * 3;
        const int h = oh + kh - 1;
        const float validf = (h >= 0 && h < HW) ? 1.f : 0.f;
        short* Abuf = A_l[buf];
        // ---- quantize prefetched A regs -> LDS buf ----
#pragma unroll
        for (int half = 0; half < 2; ++half) {
            const int bb = tid + half * 256;
            const int ow0 = (bb & 31) << 2, c0 = (bb >> 5) << 2;
            float4v xm = *(const float4v*)(xmul + r * 64 + c0);
#pragma unroll
            for (int i = 0; i < 4; ++i) xm[i] *= validf;
            short qs[4][4];
#pragma unroll
            for (int i = 0; i < 4; ++i)
#pragma unroll
                for (int j = 0; j < 4; ++j) {
                    float q = rintf(Av[half][i][j] * xm[i]);
                    q = fminf(127.f, fmaxf(-127.f, q));
                    qs[i][j] = (short)(__float_as_uint(q) >> 16);
                }
#pragma unroll
            for (int j = 0; j < 4; ++j) {
                const int ow = ow0 + j + 1 - kw;
                if (ow >= 0 && ow < HW) {
                    short4v pk = {qs[0][j], qs[1][j], qs[2][j], qs[3][j]};
                    const int pc = c0 ^ (((ow >> 2) & 7) << 3);
                    *(short4v*)(Abuf + ow * 72 + pc) = pk;
                }
            }
        }
        if (kw == 0 && tid < 16) {   // row ow=0 never written
            short4v z = {0, 0, 0, 0};
            *(short4v*)(Abuf + (tid << 2)) = z;
        }
        if (kw == 2 && tid < 16) {   // row ow=127 never written
            short4v z = {0, 0, 0, 0};
            *(short4v*)(Abuf + 127 * 72 + ((tid << 2) ^ 56)) = z;
        }
        __syncthreads();   // drains B-DMA[r] (issued one MFMA-phase ago); nothing else in flight
        if (r < 8) {       // prefetch AFTER barrier so the drain doesn't kill it
            issue_A(r + 1);
            issue_B(r + 1, B_l[buf ^ 1]);
        }
        // ---- MFMA on buf (overlaps the prefetch) ----
        const short* Bbuf = B_l[buf];
#pragma unroll
        for (int ks = 0; ks < 2; ++ks) {
            const int klog = (ks << 5) + ((lane >> 4) << 3);
            bfrag af[4], bfr[4];
#pragma unroll
            for (int mt = 0; mt < 4; ++mt) {
                const int arow = wm + (mt << 4) + (lane & 15);
                const int pk2 = klog ^ (((arow >> 2) & 7) << 3);
                af[mt] = *(const bfrag*)(Abuf + arow * 72 + pk2);
            }
#pragma unroll
            for (int nt = 0; nt < 4; ++nt) {
                const int brow = wn + (nt << 4) + (lane & 15);
                const int pkb = klog ^ ((brow & 7) << 3);
                bfr[nt] = *(const bfrag*)(Bbuf + brow * 64 + pkb);
            }
#pragma unroll
            for (int mt = 0; mt < 4; ++mt)
#pragma unroll
                for (int nt = 0; nt < 4; ++nt)
                    acc[mt][nt] = __builtin_amdgcn_mfma_f32_16x16x32_bf16(
                        af[mt], bfr[nt], acc[mt][nt], 0, 0, 0);
        }
        // no second barrier: double buffering covers the WAR hazard
    }

    const float sxsw = wsf[WS_SXSW];
#pragma unroll
    for (int mt = 0; mt < 4; ++mt)
#pragma unroll
        for (int nt = 0; nt < 4; ++nt) {
            const int ow0 = wm + (mt << 4) + ((lane >> 4) << 2);
            const int o = wn + (nt << 4) + (lane & 15);
            float4v rv;
#pragma unroll
            for (int q = 0; q < 4; ++q) rv[q] = acc[mt][nt][q] * sxsw;
            *(float4v*)(out + ((size_t)(b * OC + o) * HW + oh) * HW + ow0) = rv;
        }
}

// ---------------------------------------------------------------------------
extern "C" void kernel_launch(void* const* d_in, const int* in_sizes, int n_in,
                              void* d_out, int out_size, void* d_ws, size_t ws_size,
                              hipStream_t stream) {
    const float* in = (const float*)d_in[0];   // (16, 64, 128, 128) fp32
    const float* wt = (const float*)d_in[1];   // (128, 64, 3, 3) fp32
    float* out = (float*)d_out;                // (16, 128, 128, 128) fp32
    float* wsf = (float*)d_ws;
    short* wq_s = (short*)((char*)d_ws + WS_WQ_BYTE_OFF);

    k_absmax<<<dim3(1024 + 144), dim3(256), 0, stream>>>(in, wt, wsf);
    k_scale_wq<<<dim3(128), dim3(576), 0, stream>>>(wt, wsf, wq_s);
    k_gemm<<<dim3(BATCH * HW), dim3(256), 0, stream>>>(in, wq_s, wsf, out);
}